// Round 16
// baseline (247.130 us; speedup 1.0000x reference)
//
#include <hip/hip_runtime.h>
#include <math.h>

typedef short bf16x8 __attribute__((ext_vector_type(8)));
typedef float f32x4  __attribute__((ext_vector_type(4)));
typedef unsigned short u16;
typedef unsigned int   u32;

#define MFMA16 __builtin_amdgcn_mfma_f32_16x16x32_bf16

__device__ __forceinline__ u16 f2b(float x) {   // fp32 -> bf16 RNE
    union { float f; unsigned u; } v; v.f = x;
    unsigned r = v.u + 0x7fffu + ((v.u >> 16) & 1u);
    return (u16)(r >> 16);
}
// round-half-up bf16 (2 VALU vs 4; <=0.5ulp) — K4 Xhat/O1 quantization
__device__ __forceinline__ u16 f2bu(float x) {
    union { float f; unsigned u; } v; v.f = x;
    return (u16)((v.u + 0x8000u) >> 16);
}
__device__ __forceinline__ float blo(u32 w) {
    union { u32 u; float f; } v; v.u = w << 16; return v.f;
}
__device__ __forceinline__ float bhi(u32 w) {
    union { u32 u; float f; } v; v.u = w & 0xffff0000u; return v.f;
}
// sum 3 packed bf16 pairs in fp32 (order i0+i1+i2), repack bf16 HALF-UP via
// one v_perm_b32 (R14-verified). exp and K4 A-frags both read the STORED value.
__device__ __forceinline__ u32 add3pack(u32 x, u32 y, u32 z) {
    union { float f; u32 u; } lo, hi;
    lo.f = blo(x) + blo(y) + blo(z);
    hi.f = bhi(x) + bhi(y) + bhi(z);
    return __builtin_amdgcn_perm(hi.u + 0x8000u, lo.u + 0x8000u, 0x07060302u);
}

#define LOG2E 1.44269504088896340736f

// ---------------------------------------------------------------------------
// K1 (merged, R14-verified): blocks [0,32) weight swizzle; [32,32+SB) segment
// bounds; rest node MLP -> hb (bf16). h bit-identical to R10.
// Panel(kt,nt): 16 n-rows x 40 u16. SWZ: WB[0,5120)|V1B[5120,15360)|V2B[15360,20480)
// ---------------------------------------------------------------------------
__global__ __launch_bounds__(256) void prep_mlp_kernel(
    const float* __restrict__ x, const float* __restrict__ u,
    const int* __restrict__ batch,
    const float* __restrict__ W1, const float* __restrict__ b1,
    const float* __restrict__ W2, const float* __restrict__ b2,
    const float* __restrict__ W3, const float* __restrict__ b3,
    u16* __restrict__ hb, int N,
    const float* __restrict__ Wg, const float* __restrict__ V1g,
    const float* __restrict__ V2g, u16* __restrict__ SWZ,
    const int* __restrict__ bh, int E, int G, int* __restrict__ seg_start,
    int SB)
{
    const int b = blockIdx.x, tid = threadIdx.x;
    if (b < 32) {                       // ---- weight swizzle ----
        int idx = b * 256 + tid;        // 0..8191
        int k = idx >> 6, n = idx & 63;
        int off = ((k >> 5) * 4 + (n >> 4)) * 640 + (n & 15) * 40 + ((k >> 3) & 3) * 8 + (k & 7);
        SWZ[5120 + off] = f2b(V1g[idx]);
        if (idx < 4096) {
            SWZ[off]         = f2b(Wg[idx]);
            SWZ[15360 + off] = f2b(V2g[idx]);
        }
        return;
    }
    if (b < 32 + SB) {                  // ---- segment bounds ----
        int g = (b - 32) * 256 + tid;
        if (g > G) return;
        int lo = 0, hi = E;
        while (lo < hi) {
            int mid = (lo + hi) >> 1;
            if (bh[mid] < g) lo = mid + 1; else hi = mid;
        }
        seg_start[g] = lo;
        return;
    }
    // ---- node MLP ----
    __shared__ float inbuf[16][10];
    __shared__ float h1[16][64];
    __shared__ float h2[16][64];
    const int ni = tid >> 6, f = tid & 63;
    const int base = (b - 32 - SB) * 16;
    int nodes[4];
    #pragma unroll
    for (int s = 0; s < 4; ++s) {
        nodes[s] = min(base + s * 4 + ni, N - 1);
        if (f < 6)       inbuf[s * 4 + ni][f] = x[nodes[s] * 6 + f];
        else if (f < 10) inbuf[s * 4 + ni][f] = u[batch[nodes[s]] * 4 + (f - 6)];
    }
    __syncthreads();
    float acc[4];
    #pragma unroll
    for (int s = 0; s < 4; ++s) acc[s] = b1[f];
    #pragma unroll
    for (int k = 0; k < 10; ++k) {
        float w = W1[k * 64 + f];
        #pragma unroll
        for (int s = 0; s < 4; ++s) acc[s] = fmaf(inbuf[s * 4 + ni][k], w, acc[s]);
    }
    #pragma unroll
    for (int s = 0; s < 4; ++s) h1[s * 4 + ni][f] = fmaxf(acc[s], 0.f);
    __syncthreads();
    #pragma unroll
    for (int s = 0; s < 4; ++s) acc[s] = b2[f];
    #pragma unroll
    for (int k4 = 0; k4 < 16; ++k4) {
        float w0 = W2[(k4 * 4 + 0) * 64 + f];
        float w1 = W2[(k4 * 4 + 1) * 64 + f];
        float w2 = W2[(k4 * 4 + 2) * 64 + f];
        float w3 = W2[(k4 * 4 + 3) * 64 + f];
        #pragma unroll
        for (int s = 0; s < 4; ++s) {
            float4 hv = *(const float4*)&h1[s * 4 + ni][k4 * 4];
            acc[s] = fmaf(hv.x, w0, acc[s]);
            acc[s] = fmaf(hv.y, w1, acc[s]);
            acc[s] = fmaf(hv.z, w2, acc[s]);
            acc[s] = fmaf(hv.w, w3, acc[s]);
        }
    }
    #pragma unroll
    for (int s = 0; s < 4; ++s) h2[s * 4 + ni][f] = fmaxf(acc[s], 0.f);
    __syncthreads();
    #pragma unroll
    for (int s = 0; s < 4; ++s) acc[s] = b3[f];
    #pragma unroll
    for (int k4 = 0; k4 < 16; ++k4) {
        float w0 = W3[(k4 * 4 + 0) * 64 + f];
        float w1 = W3[(k4 * 4 + 1) * 64 + f];
        float w2 = W3[(k4 * 4 + 2) * 64 + f];
        float w3 = W3[(k4 * 4 + 3) * 64 + f];
        #pragma unroll
        for (int s = 0; s < 4; ++s) {
            float4 hv = *(const float4*)&h2[s * 4 + ni][k4 * 4];
            acc[s] = fmaf(hv.x, w0, acc[s]);
            acc[s] = fmaf(hv.y, w1, acc[s]);
            acc[s] = fmaf(hv.z, w2, acc[s]);
            acc[s] = fmaf(hv.w, w3, acc[s]);
        }
    }
    #pragma unroll
    for (int s = 0; s < 4; ++s) hb[nodes[s] * 64 + f] = f2b(acc[s]);
}

// ---------------------------------------------------------------------------
// K3: gather + Xh write + softmax denominators. R16: the idx->gather chain
// is software-pipelined — next iteration's 12 indices prefetched (clamped,
// branch-free) while this iteration's gathers are in flight (~24 loads
// outstanding; K3 was latency-bound, inferred ~70-84us from R15 budget).
// out[E..2E) moved to K4. uint4 gathers + perm pack (R12/R14-verified).
// Standalone at high occupancy (R8 lesson).
// ---------------------------------------------------------------------------
__global__ __launch_bounds__(256) void gather_stats_kernel(
    const u16* __restrict__ hb, const int* __restrict__ hidx,
    const int* __restrict__ seg_start,
    u16* __restrict__ Xh, float* __restrict__ Sinv, int E)
{
    __shared__ float ps[4][8][8];
    const int tid = threadIdx.x, lane = tid & 63, wid = tid >> 6;
    const int sub = lane >> 3, cl = lane & 7;
    const int g = blockIdx.x;
    const int e0 = seg_start[g], e1 = seg_start[g + 1];
    if (e1 <= e0) return;
    const int e1m1 = e1 - 1;

    float s[8] = {0.f, 0.f, 0.f, 0.f, 0.f, 0.f, 0.f, 0.f};
    const int base = e0 + wid * 8 + sub;

    int i0c[4], i1c[4], i2c[4];
    #pragma unroll
    for (int j = 0; j < 4; ++j) {                 // prime the pipeline
        int ec = min(base + j * 32, e1m1);
        i0c[j] = hidx[ec]; i1c[j] = hidx[E + ec]; i2c[j] = hidx[2 * E + ec];
    }

    for (int e = base; e < e1; e += 128) {
        int i0n[4], i1n[4], i2n[4];
        const int en = e + 128;
        #pragma unroll
        for (int j = 0; j < 4; ++j) {             // prefetch next indices
            int ec = min(en + j * 32, e1m1);      // clamped: always safe
            i0n[j] = hidx[ec]; i1n[j] = hidx[E + ec]; i2n[j] = hidx[2 * E + ec];
        }
        #pragma unroll
        for (int j = 0; j < 4; ++j) {
            int ee = e + j * 32;
            uint4 A0 = *(const uint4*)(hb + (size_t)i0c[j] * 64 + cl * 8);
            uint4 A1 = *(const uint4*)(hb + (size_t)i1c[j] * 64 + cl * 8);
            uint4 A2 = *(const uint4*)(hb + (size_t)i2c[j] * 64 + cl * 8);
            u32 w0 = add3pack(A0.x, A1.x, A2.x);
            u32 w1 = add3pack(A0.y, A1.y, A2.y);
            u32 w2 = add3pack(A0.z, A1.z, A2.z);
            u32 w3 = add3pack(A0.w, A1.w, A2.w);
            if (ee < e1) {
                uint4 W; W.x = w0; W.y = w1; W.z = w2; W.w = w3;
                *(uint4*)(Xh + (size_t)ee * 64 + cl * 8) = W;
                s[0] += __expf(blo(w0)); s[1] += __expf(bhi(w0));
                s[2] += __expf(blo(w1)); s[3] += __expf(bhi(w1));
                s[4] += __expf(blo(w2)); s[5] += __expf(bhi(w2));
                s[6] += __expf(blo(w3)); s[7] += __expf(bhi(w3));
            }
        }
        #pragma unroll
        for (int j = 0; j < 4; ++j) {
            i0c[j] = i0n[j]; i1c[j] = i1n[j]; i2c[j] = i2n[j];
        }
    }
    #pragma unroll
    for (int k = 0; k < 8; ++k) {
        s[k] += __shfl_xor(s[k], 8);
        s[k] += __shfl_xor(s[k], 16);
        s[k] += __shfl_xor(s[k], 32);
    }
    if (lane < 8) {
        #pragma unroll
        for (int k = 0; k < 8; ++k) ps[wid][lane][k] = s[k];
    }
    __syncthreads();
    if (tid < 64) {
        int c8 = tid >> 3, cc = tid & 7;
        float S = ps[0][c8][cc] + ps[1][c8][cc] + ps[2][c8][cc] + ps[3][c8][cc];
        Sinv[g * 64 + tid] = 1.f / S;
    }
}

// ---------------------------------------------------------------------------
// K4: paired-tile MFMA chain (R13/R15-verified, ~84us). R16 delta: also
// writes out[E..2E) = (float)g in the packed-store guard (moved from K3;
// +2 float4 stores/pair-iter, WRITE 4.6->9.1MB — VMEM there is negligible).
// Locked: stride 72 (16B-aligned, R12/R13), f2bu epilogues, exp2-folded
// coef (R15), 256-thr + (256,3) (R9), weights in LDS (R5), Xh streamed w/
// prefetch (R7). LDS: 40960(SW) + 9216(XT) = 50176 B -> 3 blocks/CU.
// ---------------------------------------------------------------------------
__global__ __launch_bounds__(256, 3) void mfma_seg_kernel(
    const u16* __restrict__ Xh, const int* __restrict__ seg_start,
    const u16* __restrict__ SWZ, const float* __restrict__ Sinv,
    const float* __restrict__ c1g, const float* __restrict__ c2g,
    const float* __restrict__ V3g, const float* __restrict__ c3g,
    float* __restrict__ out, int E)
{
    __shared__ u16 SW[20480];          // WB[0,5120)+V1B[5120,15360)+V2B[15360,20480)
    __shared__ u16 XT_all[4][16 * 72]; // per-wave transpose tile, stride 72

    const int tid = threadIdx.x, lane = tid & 63, wid = tid >> 6;
    const int nl = lane & 15, rq = lane >> 4;
    const int g = blockIdx.x;
    const int e0 = seg_start[g], e1 = seg_start[g + 1];
    const int L = e1 - e0;
    if (L <= 0) return;
    const int e1m1 = e1 - 1;

    {   // stage pre-swizzled W+V1+V2: 40960 B = 2560 uint4
        const uint4* src = (const uint4*)SWZ;
        uint4* dst = (uint4*)SW;
        for (int i = tid; i < 2560; i += 256) dst[i] = src[i];
    }
    __syncthreads();
    const u16* WB  = SW;
    const u16* V1B = SW + 5120;
    const u16* V2B = SW + 15360;

    // identity B-frags for X C-layout redistribution (exact in bf16)
    bf16x8 I0, I1;
    #pragma unroll
    for (int j = 0; j < 8; ++j) {
        I0[j] = (rq * 8 + j == nl)      ? (short)0x3F80 : (short)0;
        I1[j] = (rq * 8 + j == nl + 16) ? (short)0x3F80 : (short)0;
    }

    float l2d[4], c1v[4], c2v[4], v3v[4];
    #pragma unroll
    for (int nt = 0; nt < 4; ++nt) {
        int col = nt * 16 + nl;
        l2d[nt] = __log2f(Sinv[g * 64 + col]);   // log2(dinv), hoisted
        c1v[nt] = c1g[col];
        c2v[nt] = c2g[col];
        v3v[nt] = V3g[col];
    }
    const float c3s = c3g[0];
    const float gf  = (float)g;
    const float4 gf4 = make_float4(gf, gf, gf, gf);
    u16* XT = XT_all[wid];
    const f32x4 zf = {0.f, 0.f, 0.f, 0.f};

    auto loadA = [&](int tt, bf16x8& A0, bf16x8& A1) {
        const u16* xp = Xh + (size_t)min(e0 + tt * 16 + nl, e1m1) * 64 + rq * 8;
        A0 = *(const bf16x8*)(xp);
        A1 = *(const bf16x8*)(xp + 32);
    };

    int t = wid;
    bf16x8 p0 = {}, p1 = {};
    if (t * 16 < L) loadA(t, p0, p1);

    for (; t * 16 < L; t += 8) {
        const int eB1 = e0 + t * 16;
        const int eB2 = eB1 + 64;                 // tile t+4 (may be phantom)

        bf16x8 a0 = p0, a1 = p1;                  // tile 1 (prefetched)
        bf16x8 a2, a3;
        loadA(t + 4, a2, a3);                     // tile 2 (clamped)
        if ((t + 8) * 16 < L) loadA(t + 8, p0, p1);  // prefetch next pair's 1st

        // xv in C-layout via identity MFMA, both tiles
        f32x4 xc1[4], xc2[4];
        xc1[0] = MFMA16(a0, I0, zf, 0, 0, 0);
        xc1[1] = MFMA16(a0, I1, zf, 0, 0, 0);
        xc1[2] = MFMA16(a1, I0, zf, 0, 0, 0);
        xc1[3] = MFMA16(a1, I1, zf, 0, 0, 0);
        xc2[0] = MFMA16(a2, I0, zf, 0, 0, 0);
        xc2[1] = MFMA16(a2, I1, zf, 0, 0, 0);
        xc2[2] = MFMA16(a3, I0, zf, 0, 0, 0);
        xc2[3] = MFMA16(a3, I1, zf, 0, 0, 0);

        // ---- layer W (B-frags shared) ----
        f32x4 acc1[4] = {zf, zf, zf, zf}, acc2t[4] = {zf, zf, zf, zf};
        #pragma unroll
        for (int nt = 0; nt < 4; ++nt) {
            bf16x8 b0 = *(const bf16x8*)(WB + (0 * 4 + nt) * 640 + nl * 40 + rq * 8);
            acc1[nt]  = MFMA16(a0, b0, acc1[nt], 0, 0, 0);
            acc2t[nt] = MFMA16(a2, b0, acc2t[nt], 0, 0, 0);
            bf16x8 b1 = *(const bf16x8*)(WB + (1 * 4 + nt) * 640 + nl * 40 + rq * 8);
            acc1[nt]  = MFMA16(a1, b1, acc1[nt], 0, 0, 0);
            acc2t[nt] = MFMA16(a3, b1, acc2t[nt], 0, 0, 0);
        }
        // Xhat epilogue: coef = exp2(xv*log2e + l2d)  [R15]
        #pragma unroll
        for (int nt = 0; nt < 4; ++nt) {
            #pragma unroll
            for (int r = 0; r < 4; ++r) {
                float coef = __builtin_amdgcn_exp2f(
                    fmaf(xc1[nt][r], LOG2E, l2d[nt]));
                XT[(rq * 4 + r) * 72 + nt * 16 + nl] =
                    f2bu(coef * fmaxf(acc1[nt][r], 0.f));
            }
        }
        bf16x8 x2a = *(const bf16x8*)(XT + nl * 72 + rq * 8);
        bf16x8 x3a = *(const bf16x8*)(XT + nl * 72 + 32 + rq * 8);
        #pragma unroll
        for (int nt = 0; nt < 4; ++nt) {
            #pragma unroll
            for (int r = 0; r < 4; ++r) {
                float coef = __builtin_amdgcn_exp2f(
                    fmaf(xc2[nt][r], LOG2E, l2d[nt]));
                XT[(rq * 4 + r) * 72 + nt * 16 + nl] =
                    f2bu(coef * fmaxf(acc2t[nt][r], 0.f));
            }
        }
        bf16x8 x2b = *(const bf16x8*)(XT + nl * 72 + rq * 8);
        bf16x8 x3b = *(const bf16x8*)(XT + nl * 72 + 32 + rq * 8);

        // ---- layer V1 (B-frags shared) ----
        f32x4 va[4], vb[4];
        #pragma unroll
        for (int nt = 0; nt < 4; ++nt) {
            va[nt][0] = c1v[nt]; va[nt][1] = c1v[nt];
            va[nt][2] = c1v[nt]; va[nt][3] = c1v[nt];
            vb[nt] = va[nt];
        }
        #pragma unroll
        for (int nt = 0; nt < 4; ++nt) {
            bf16x8 b0 = *(const bf16x8*)(V1B + (0 * 4 + nt) * 640 + nl * 40 + rq * 8);
            va[nt] = MFMA16(a0, b0, va[nt], 0, 0, 0);
            vb[nt] = MFMA16(a2, b0, vb[nt], 0, 0, 0);
            bf16x8 b1 = *(const bf16x8*)(V1B + (1 * 4 + nt) * 640 + nl * 40 + rq * 8);
            va[nt] = MFMA16(a1, b1, va[nt], 0, 0, 0);
            vb[nt] = MFMA16(a3, b1, vb[nt], 0, 0, 0);
        }
        #pragma unroll
        for (int nt = 0; nt < 4; ++nt) {
            bf16x8 b2 = *(const bf16x8*)(V1B + (2 * 4 + nt) * 640 + nl * 40 + rq * 8);
            va[nt] = MFMA16(x2a, b2, va[nt], 0, 0, 0);
            vb[nt] = MFMA16(x2b, b2, vb[nt], 0, 0, 0);
            bf16x8 b3 = *(const bf16x8*)(V1B + (3 * 4 + nt) * 640 + nl * 40 + rq * 8);
            va[nt] = MFMA16(x3a, b3, va[nt], 0, 0, 0);
            vb[nt] = MFMA16(x3b, b3, vb[nt], 0, 0, 0);
        }
        // O1 epilogue tile1 -> XT, read o-frags; then tile2
        #pragma unroll
        for (int nt = 0; nt < 4; ++nt) {
            #pragma unroll
            for (int r = 0; r < 4; ++r)
                XT[(rq * 4 + r) * 72 + nt * 16 + nl] = f2bu(fmaxf(va[nt][r], 0.f));
        }
        bf16x8 o0a = *(const bf16x8*)(XT + nl * 72 + rq * 8);
        bf16x8 o1a = *(const bf16x8*)(XT + nl * 72 + 32 + rq * 8);
        #pragma unroll
        for (int nt = 0; nt < 4; ++nt) {
            #pragma unroll
            for (int r = 0; r < 4; ++r)
                XT[(rq * 4 + r) * 72 + nt * 16 + nl] = f2bu(fmaxf(vb[nt][r], 0.f));
        }
        bf16x8 o0b = *(const bf16x8*)(XT + nl * 72 + rq * 8);
        bf16x8 o1b = *(const bf16x8*)(XT + nl * 72 + 32 + rq * 8);

        // ---- layer V2 (B-frags shared) ----
        f32x4 wa[4], wb2[4];
        #pragma unroll
        for (int nt = 0; nt < 4; ++nt) {
            wa[nt][0] = c2v[nt]; wa[nt][1] = c2v[nt];
            wa[nt][2] = c2v[nt]; wa[nt][3] = c2v[nt];
            wb2[nt] = wa[nt];
        }
        #pragma unroll
        for (int nt = 0; nt < 4; ++nt) {
            bf16x8 b0 = *(const bf16x8*)(V2B + (0 * 4 + nt) * 640 + nl * 40 + rq * 8);
            wa[nt]  = MFMA16(o0a, b0, wa[nt], 0, 0, 0);
            wb2[nt] = MFMA16(o0b, b0, wb2[nt], 0, 0, 0);
            bf16x8 b1 = *(const bf16x8*)(V2B + (1 * 4 + nt) * 640 + nl * 40 + rq * 8);
            wa[nt]  = MFMA16(o1a, b1, wa[nt], 0, 0, 0);
            wb2[nt] = MFMA16(o1b, b1, wb2[nt], 0, 0, 0);
        }

        // ---- V3 + sigmoid, both tiles ----
        float sra[4], srb[4];
        #pragma unroll
        for (int r = 0; r < 4; ++r) {
            float u1 = 0.f, u2 = 0.f;
            #pragma unroll
            for (int nt = 0; nt < 4; ++nt) {
                u1 = fmaf(fmaxf(wa[nt][r],  0.f), v3v[nt], u1);
                u2 = fmaf(fmaxf(wb2[nt][r], 0.f), v3v[nt], u2);
            }
            u1 += __shfl_xor(u1, 1); u2 += __shfl_xor(u2, 1);
            u1 += __shfl_xor(u1, 2); u2 += __shfl_xor(u2, 2);
            u1 += __shfl_xor(u1, 4); u2 += __shfl_xor(u2, 4);
            u1 += __shfl_xor(u1, 8); u2 += __shfl_xor(u2, 8);
            sra[r] = 1.f / (1.f + __expf(-(u1 + c3s)));
            srb[r] = 1.f / (1.f + __expf(-(u2 + c3s)));
        }
        if (nl == 0) {
            const int ra = eB1 + rq * 4;
            if (ra + 3 < e1) {                    // packed float4 stores
                *(float4*)(out + ra) = make_float4(sra[0], sra[1], sra[2], sra[3]);
                *(float4*)(out + E + ra) = gf4;   // output 1 (moved from K3)
            } else {
                #pragma unroll
                for (int r = 0; r < 4; ++r)
                    if (ra + r < e1) { out[ra + r] = sra[r]; out[E + ra + r] = gf; }
            }
            const int rb = eB2 + rq * 4;
            if (rb + 3 < e1) {
                *(float4*)(out + rb) = make_float4(srb[0], srb[1], srb[2], srb[3]);
                *(float4*)(out + E + rb) = gf4;
            } else {
                #pragma unroll
                for (int r = 0; r < 4; ++r)
                    if (rb + r < e1) { out[rb + r] = srb[r]; out[E + rb + r] = gf; }
            }
        }
    }
}

// ---------------------------------------------------------------------------
extern "C" void kernel_launch(void* const* d_in, const int* in_sizes, int n_in,
                              void* d_out, int out_size, void* d_ws, size_t ws_size,
                              hipStream_t stream) {
    const float* x     = (const float*)d_in[0];
    const float* u     = (const float*)d_in[1];
    const int*   batch = (const int*)  d_in[2];
    const int*   hidx  = (const int*)  d_in[3];
    const int*   bh    = (const int*)  d_in[4];
    const float* W1 = (const float*)d_in[6];
    const float* b1 = (const float*)d_in[7];
    const float* W2 = (const float*)d_in[8];
    const float* b2 = (const float*)d_in[9];
    const float* W3 = (const float*)d_in[10];
    const float* b3 = (const float*)d_in[11];
    const float* Wg = (const float*)d_in[12];
    const float* V1 = (const float*)d_in[13];
    const float* c1 = (const float*)d_in[14];
    const float* V2 = (const float*)d_in[15];
    const float* c2 = (const float*)d_in[16];
    const float* V3 = (const float*)d_in[17];
    const float* c3 = (const float*)d_in[18];

    const int N = in_sizes[0] / 6;
    const int G = in_sizes[1] / 4;
    const int E = in_sizes[4];

    // ws layout
    char* ws = (char*)d_ws;
    size_t off = 0;
    u16* hb = (u16*)(ws + off);            off += (size_t)N * 64 * 2;
    int* seg_start = (int*)(ws + off);     off += ((size_t)G + 1) * 4;
    off = (off + 255) & ~(size_t)255;
    u16* SWZ = (u16*)(ws + off);           off += 20480 * 2;
    float* Sinv = (float*)(ws + off);      off += (size_t)G * 64 * 4;
    off = (off + 255) & ~(size_t)255;
    u16* Xh = (u16*)(ws + off);            off += (size_t)E * 64 * 2;
    float* out = (float*)d_out;

    const int SB = (G + 256) / 256;
    const int NB = (N + 15) / 16;
    prep_mlp_kernel<<<32 + SB + NB, 256, 0, stream>>>(
        x, u, batch, W1, b1, W2, b2, W3, b3, hb, N,
        Wg, V1, V2, SWZ, bh, E, G, seg_start, SB);
    gather_stats_kernel<<<G, 256, 0, stream>>>(hb, hidx, seg_start, Xh, Sinv, E);
    mfma_seg_kernel<<<G, 256, 0, stream>>>(
        Xh, seg_start, SWZ, Sinv, c1, c2, V3, c3, out, E);
}